// Round 1
// baseline (14435.611 us; speedup 1.0000x reference)
//
#include <hip/hip_runtime.h>
#include <cstdint>
#include <cstddef>

#define NB 32       // batch
#define NT 512      // time steps
#define ND 512      // input dim D
#define NH 1024     // hidden H
#define NC4 4608    // 4H + 4*HH (fused GEMM N)
#define NBLK 256    // main-kernel grid

typedef short sh8 __attribute__((ext_vector_type(8)));   // 8 bf16 (raw bits)
typedef float f4  __attribute__((ext_vector_type(4)));
typedef unsigned int u4 __attribute__((ext_vector_type(4)));

__device__ __forceinline__ unsigned short f2bf(float x) {
  union { float f; unsigned u; } v; v.f = x;
  unsigned r = v.u + 0x7FFFu + ((v.u >> 16) & 1u);   // RNE
  return (unsigned short)(r >> 16);
}
__device__ __forceinline__ float bf2f(unsigned short b) {
  union { unsigned u; float f; } v; v.u = ((unsigned)b) << 16; return v.f;
}
__device__ __forceinline__ float blo(unsigned w) { union { unsigned u; float f; } v; v.u = w << 16; return v.f; }
__device__ __forceinline__ float bhi(unsigned w) { union { unsigned u; float f; } v; v.u = w & 0xFFFF0000u; return v.f; }

// ---------------------------------------------------------------------------
// prep: hyper gate weights -> bf16 transposed [4][j=128][k=128];
//       pz weights -> fp32 [3][c=16][k=128]; zero h ping-pong buf0; cnt=0
// ---------------------------------------------------------------------------
__global__ __launch_bounds__(256) void k_prep(
    const float* __restrict__ wih, const float* __restrict__ wgh,
    const float* __restrict__ wfh, const float* __restrict__ woh,
    const float* __restrict__ pzx, const float* __restrict__ pzh,
    const float* __restrict__ pzb,
    unsigned short* __restrict__ whht, float* __restrict__ pzt,
    unsigned short* __restrict__ hbuf, int* __restrict__ cnt)
{
  int idx = blockIdx.x * 256 + threadIdx.x;
  if (idx < 65536) {  // 4*128*128
    int g = idx >> 14, r = idx & 16383, j = r >> 7, k = r & 127;
    const float* w = (g == 0) ? wih : (g == 1) ? wgh : (g == 2) ? wfh : woh;
    whht[idx] = f2bf(w[k * 128 + j]);
  }
  if (idx < 6144) {   // 3*16*128
    int r = idx & 2047, c = r >> 7, k = r & 127;
    int kind = idx >> 11;
    const float* p = (kind == 0) ? pzx : (kind == 1) ? pzh : pzb;
    pzt[idx] = p[k * 16 + c];
    (void)c; (void)k;
  }
  if (idx < 16384) ((unsigned int*)hbuf)[idx] = 0u;  // zero buf0 (32*1024 bf16)
  if (idx == 0) cnt[0] = 0;
}

// ---------------------------------------------------------------------------
// transpose Wcat -> bf16 [n=4608][k=512]: n<4096 from Wm[:512], else Wi/g/f/o_x
// ---------------------------------------------------------------------------
__global__ __launch_bounds__(256) void k_twcat(
    const float* __restrict__ wm, const float* __restrict__ wix,
    const float* __restrict__ wgx, const float* __restrict__ wfx,
    const float* __restrict__ wox, unsigned short* __restrict__ dst)
{
  __shared__ float tile[32][33];
  int bx = blockIdx.x % 144, by = blockIdx.x / 144;
  int n0 = bx * 32, k0 = by * 32;
  int tx = threadIdx.x & 31, ty = threadIdx.x >> 5;
  #pragma unroll
  for (int i = 0; i < 4; i++) {
    int k = k0 + ty + i * 8, n = n0 + tx;
    float v;
    if (n < 4096) v = wm[(size_t)k * 4096 + n];
    else {
      int nn = n - 4096, g = nn >> 7, j = nn & 127;
      const float* w = (g == 0) ? wix : (g == 1) ? wgx : (g == 2) ? wfx : wox;
      v = w[k * 128 + j];
    }
    tile[ty + i * 8][tx] = v;
  }
  __syncthreads();
  #pragma unroll
  for (int i = 0; i < 4; i++)
    dst[(size_t)(n0 + ty + i * 8) * 512 + k0 + tx] = f2bf(tile[tx][ty + i * 8]);
}

// transpose Wm[512:] -> bf16 [n=4096][k=1024]
__global__ __launch_bounds__(256) void k_twmh(
    const float* __restrict__ wm, unsigned short* __restrict__ dst)
{
  __shared__ float tile[32][33];
  int bx = blockIdx.x % 128, by = blockIdx.x / 128;
  int n0 = bx * 32, k0 = by * 32;
  int tx = threadIdx.x & 31, ty = threadIdx.x >> 5;
  #pragma unroll
  for (int i = 0; i < 4; i++)
    tile[ty + i * 8][tx] = wm[(size_t)(512 + k0 + ty + i * 8) * 4096 + n0 + tx];
  __syncthreads();
  #pragma unroll
  for (int i = 0; i < 4; i++)
    dst[(size_t)(n0 + ty + i * 8) * 1024 + k0 + tx] = f2bf(tile[tx][ty + i * 8]);
}

// ---------------------------------------------------------------------------
// Precompute GEMM: PreAll[t*32+b][n] = bf16( x[b*512+t][:] @ Wcat[:,n] )
// M=16384 K=512 N=4608, bf16 MFMA 16x16x32, 128x128 tile, 4 waves (2x2 of 64x64)
// ---------------------------------------------------------------------------
__global__ __launch_bounds__(256) void k_gemm(
    const float* __restrict__ x, const unsigned short* __restrict__ wt,
    unsigned short* __restrict__ preall)
{
  __shared__ unsigned short la[4096];  // [128 rows][32 k], XOR-swizzled 16B granules
  __shared__ unsigned short lb[4096];
  int bid = blockIdx.x;
  int mb = bid % 128, nb = bid / 128;
  int m0 = mb * 128, n0 = nb * 128;
  int tid = threadIdx.x;
  int lane = tid & 63, wid = tid >> 6;
  int wr = (wid >> 1) * 64, wc = (wid & 1) * 64;
  f4 acc[4][4] = {};
  for (int kt = 0; kt < 16; kt++) {
    int k0 = kt * 32;
    __syncthreads();
    {   // stage A (fp32 -> bf16): 2 threads/row, 16 floats each
      int r = tid >> 1, kh = (tid & 1) * 16;
      const float4* srcA = (const float4*)(x + (size_t)(m0 + r) * 512 + k0 + kh);
      unsigned pk[8];
      #pragma unroll
      for (int q = 0; q < 4; q++) {
        float4 f = srcA[q];
        pk[q * 2]     = (unsigned)f2bf(f.x) | ((unsigned)f2bf(f.y) << 16);
        pk[q * 2 + 1] = (unsigned)f2bf(f.z) | ((unsigned)f2bf(f.w) << 16);
      }
      int base = r * 64 + kh * 2;
      u4 v0 = {pk[0], pk[1], pk[2], pk[3]}, v1 = {pk[4], pk[5], pk[6], pk[7]};
      *(u4*)((char*)la + ((base)      ^ ((r & 7) << 4))) = v0;
      *(u4*)((char*)la + ((base + 16) ^ ((r & 7) << 4))) = v1;
    }
    {   // stage B (already bf16): 2 threads/row, 16 bf16 each
      int r = tid >> 1, kh = (tid & 1) * 16;
      const u4* srcB = (const u4*)(wt + (size_t)(n0 + r) * 512 + k0 + kh);
      u4 v0 = srcB[0], v1 = srcB[1];
      int base = r * 64 + kh * 2;
      *(u4*)((char*)lb + ((base)      ^ ((r & 7) << 4))) = v0;
      *(u4*)((char*)lb + ((base + 16) ^ ((r & 7) << 4))) = v1;
    }
    __syncthreads();
    int fo = (lane >> 4) * 16;
    sh8 af[4], bfr[4];
    #pragma unroll
    for (int mt = 0; mt < 4; mt++) {
      int r = wr + mt * 16 + (lane & 15);
      af[mt] = *(sh8*)((char*)la + ((r * 64 + fo) ^ ((r & 7) << 4)));
    }
    #pragma unroll
    for (int nt = 0; nt < 4; nt++) {
      int r = wc + nt * 16 + (lane & 15);
      bfr[nt] = *(sh8*)((char*)lb + ((r * 64 + fo) ^ ((r & 7) << 4)));
    }
    #pragma unroll
    for (int mt = 0; mt < 4; mt++)
      #pragma unroll
      for (int nt = 0; nt < 4; nt++)
        acc[mt][nt] = __builtin_amdgcn_mfma_f32_16x16x32_bf16(af[mt], bfr[nt], acc[mt][nt], 0, 0, 0);
  }
  // C write: row m -> (b=m>>9, t=m&511) -> PreAll row t*32+b, bf16
  #pragma unroll
  for (int mt = 0; mt < 4; mt++)
    #pragma unroll
    for (int nt = 0; nt < 4; nt++) {
      f4 a = acc[mt][nt];
      #pragma unroll
      for (int rr = 0; rr < 4; rr++) {
        int m = m0 + wr + mt * 16 + (lane >> 4) * 4 + rr;
        int n = n0 + wc + nt * 16 + (lane & 15);
        int b = m >> 9, t = m & 511;
        preall[(size_t)(t * 32 + b) * NC4 + n] = f2bf(a[rr]);
      }
    }
}

// ---------------------------------------------------------------------------
// Hyper chain: 1 block per batch row, 512 threads = (gate g, j).
// Gate weights live in VGPRs (bf16). Produces z[t][b][48] fp32.
// ---------------------------------------------------------------------------
__global__ __launch_bounds__(512) void k_hyper(
    const unsigned short* __restrict__ preall,  // xproj at cols 4096+
    const unsigned short* __restrict__ whht,    // [4][128][128] bf16
    const float* __restrict__ pzt,              // [3][16][128] fp32
    const float* __restrict__ bi, const float* __restrict__ bg,
    const float* __restrict__ bff, const float* __restrict__ bo,
    const float* __restrict__ lnig, const float* __restrict__ lnib,
    const float* __restrict__ lngg, const float* __restrict__ lngb,
    const float* __restrict__ lnfg, const float* __restrict__ lnfb,
    const float* __restrict__ lnog, const float* __restrict__ lnob,
    const float* __restrict__ lncg, const float* __restrict__ lncb,
    const float* __restrict__ pzxb, const float* __restrict__ pzhb,
    const float* __restrict__ pzbb,
    float* __restrict__ zout)
{
  const int b = blockIdx.x;
  const int tid = threadIdx.x;
  const int g = tid >> 7, j = tid & 127;
  __shared__ __align__(16) float hh[128];
  __shared__ __align__(16) float ch[128];
  __shared__ float act[4][128];
  __shared__ float red[20];
  __shared__ __align__(16) float pzl[48 * 132];  // padded rows (132) -> conflict-free

  u4 wreg[16];  // 128 bf16 weights for column (g,j)
  {
    const u4* wsrc = (const u4*)(whht + (size_t)(g * 128 + j) * 128);
    #pragma unroll
    for (int i = 0; i < 16; i++) wreg[i] = wsrc[i];
  }
  for (int i = tid; i < 6144; i += 512)
    pzl[(i >> 7) * 132 + (i & 127)] = pzt[i];

  float bias = ((g == 0) ? bi : (g == 1) ? bg : (g == 2) ? bff : bo)[j];
  float lgam = ((g == 0) ? lnig : (g == 1) ? lngg : (g == 2) ? lnfg : lnog)[j];
  float lbet = ((g == 0) ? lnib : (g == 1) ? lngb : (g == 2) ? lnfb : lnob)[j];
  float lcg = 0.f, lcb = 0.f;
  if (tid < 128) { lcg = lncg[tid]; lcb = lncb[tid]; hh[tid] = 0.f; ch[tid] = 0.f; }
  float zbias = 0.f;
  if (tid < 48) {
    int kind = tid >> 4, c = tid & 15;
    zbias = ((kind == 0) ? pzxb : (kind == 1) ? pzhb : pzbb)[c];
  }
  __syncthreads();

  const f4* h4 = (const f4*)hh;
  for (int t = 0; t < NT; t++) {
    float xp = bf2f(preall[(size_t)(t * 32 + b) * NC4 + 4096 + tid]);
    float s = bias;
    #pragma unroll
    for (int i = 0; i < 16; i++) {
      u4 w = wreg[i];
      f4 ha = h4[2 * i], hb = h4[2 * i + 1];
      s += blo(w.x) * ha[0] + bhi(w.x) * ha[1] + blo(w.y) * ha[2] + bhi(w.y) * ha[3]
         + blo(w.z) * hb[0] + bhi(w.z) * hb[1] + blo(w.w) * hb[2] + bhi(w.w) * hb[3];
    }
    s += xp;
    float s1 = s, s2 = s * s;
    #pragma unroll
    for (int m = 1; m < 64; m <<= 1) { s1 += __shfl_xor(s1, m); s2 += __shfl_xor(s2, m); }
    if ((tid & 63) == 0) { int w = tid >> 6; red[w * 2] = s1; red[w * 2 + 1] = s2; }
    __syncthreads();
    float sum = red[4 * g] + red[4 * g + 2], sq = red[4 * g + 1] + red[4 * g + 3];
    float mean = sum * 0.0078125f;
    float var = sq * 0.0078125f - mean * mean;
    float xn = (s - mean) * rsqrtf(var + 1e-5f) * lgam + lbet;
    float a = (g == 1) ? tanhf(xn) : 1.f / (1.f + __expf(-xn));
    act[g][j] = a;
    __syncthreads();
    if (tid < 128) {
      float cn = act[2][tid] * ch[tid] + act[0][tid] * act[1][tid];
      ch[tid] = cn;
      float c1 = cn, c2 = cn * cn;
      #pragma unroll
      for (int m = 1; m < 64; m <<= 1) { c1 += __shfl_xor(c1, m); c2 += __shfl_xor(c2, m); }
      if ((tid & 63) == 0) { int w = tid >> 6; red[16 + w * 2] = c1; red[16 + w * 2 + 1] = c2; }
    }
    __syncthreads();
    if (tid < 128) {
      float sum2 = red[16] + red[18], sq2 = red[17] + red[19];
      float mean2 = sum2 * 0.0078125f, var2 = sq2 * 0.0078125f - mean2 * mean2;
      float cn = ch[tid];
      hh[tid] = act[3][tid] * tanhf((cn - mean2) * rsqrtf(var2 + 1e-5f) * lcg + lcb);
    }
    __syncthreads();
    if (tid < 48) {   // z = hh_new @ pz*_w + pz*_b
      const f4* pr = (const f4*)(pzl + tid * 132);
      float zv = zbias;
      #pragma unroll 8
      for (int q = 0; q < 32; q++) {
        f4 p = pr[q], hv = h4[q];
        zv += p[0] * hv[0] + p[1] * hv[1] + p[2] * hv[2] + p[3] * hv[3];
      }
      zout[(size_t)(t * 32 + b) * 48 + tid] = zv;
    }
    __syncthreads();
  }
}

// ---------------------------------------------------------------------------
// Main recurrence: persistent 256 blocks x 256 thr. Block owns 4 h-cols
// (16 gate-cols). W slice in LDS (bf16, swizzled). One grid barrier/step.
// ---------------------------------------------------------------------------
__global__ __launch_bounds__(256) void k_main(
    const unsigned short* __restrict__ preall,
    const unsigned short* __restrict__ wmht,
    const float* __restrict__ zbuf,
    const float* __restrict__ pdx, const float* __restrict__ pdh,
    const float* __restrict__ pbw, const float* __restrict__ pbb,
    unsigned short* __restrict__ hbuf,    // [2][32][1024] bf16 ping-pong
    float* __restrict__ out,
    int* __restrict__ cnt)
{
  __shared__ unsigned short wlds[16 * 1024];  // [n=16][k=1024] bf16, XOR-swizzled
  __shared__ float red[8 * 272];              // [wave*2+mt][16 rows *17 + col]
  __shared__ __align__(16) float zl[32 * 48];
  __shared__ float clds[128];
  __shared__ float pdl[3][4][4];
  __shared__ float pbbl[4];

  const int tid = threadIdx.x;
  const int lane = tid & 63, wid = tid >> 6;
  const int jh0 = blockIdx.x * 4;

  {   // stage weight slice once: cols {gate*1024 + jh0 + jo}
    int n = tid >> 4, kc = (tid & 15) * 64;
    int gate = n >> 2, jo = n & 3;
    const unsigned short* src = wmht + (size_t)(gate * NH + jh0 + jo) * NH + kc;
    #pragma unroll
    for (int i = 0; i < 8; i++) {
      sh8 v = *(const sh8*)(src + i * 8);
      int byte = n * 2048 + (kc + i * 8) * 2;
      *(sh8*)((char*)wlds + (byte ^ ((n & 7) << 4))) = v;
    }
  }
  if (tid < 128) clds[tid] = 0.f;
  if (tid < 48) {
    int kind = tid >> 4, e = (tid >> 2) & 3, jo = tid & 3;
    const float* p = (kind == 0) ? pdx : (kind == 1) ? pdh : pbw;
    pdl[kind][e][jo] = p[e * NH + jh0 + jo];
  }
  if (tid < 4) pbbl[tid] = pbb[jh0 + tid];
  __syncthreads();

  int tgt = 0;
  for (int t = 0; t < NT; t++) {
    const unsigned short* hcur = hbuf + (t & 1) * (NB * NH);
    if (tid < 192) {   // stage z[t] (32x48 fp32) into LDS
      const f4* zs = (const f4*)(zbuf + (size_t)t * NB * 48) + tid * 2;
      f4 a = zs[0], bq = zs[1];
      f4* zd = (f4*)zl + tid * 2;
      zd[0] = a; zd[1] = bq;
    }
    float wx0 = 0, wx1 = 0, wx2 = 0, wx3 = 0;   // Wx prefetch (hidden under MFMA)
    if (tid < 128) {
      int b = tid >> 2, jo = tid & 3;
      const unsigned short* ps = preall + (size_t)(t * NB + b) * NC4 + jh0 + jo;
      wx0 = bf2f(ps[0]); wx1 = bf2f(ps[NH]); wx2 = bf2f(ps[2 * NH]); wx3 = bf2f(ps[3 * NH]);
    }
    // W_h partial: wave wid covers K-quarter; A from global h (bf16), B from LDS
    f4 acc0 = {0, 0, 0, 0}, acc1 = {0, 0, 0, 0};
    {
      int kq = wid * 256;
      int koff = (lane >> 4) * 8;
      int n = lane & 15;
      #pragma unroll
      for (int ks = 0; ks < 8; ks++) {
        int kb = kq + ks * 32;
        int byte = n * 2048 + (kb + koff) * 2;
        sh8 bfr = *(sh8*)((char*)wlds + (byte ^ ((n & 7) << 4)));
        sh8 a0 = *(const sh8*)(hcur + (lane & 15) * NH + kb + koff);
        sh8 a1 = *(const sh8*)(hcur + (16 + (lane & 15)) * NH + kb + koff);
        acc0 = __builtin_amdgcn_mfma_f32_16x16x32_bf16(a0, bfr, acc0, 0, 0, 0);
        acc1 = __builtin_amdgcn_mfma_f32_16x16x32_bf16(a1, bfr, acc1, 0, 0, 0);
      }
    }
    {
      int col = lane & 15, r0 = (lane >> 4) * 4;
      int base0 = (wid * 2) * 272, base1 = (wid * 2 + 1) * 272;
      #pragma unroll
      for (int rr = 0; rr < 4; rr++) {
        red[base0 + (r0 + rr) * 17 + col] = acc0[rr];
        red[base1 + (r0 + rr) * 17 + col] = acc1[rr];
      }
    }
    __syncthreads();
    if (tid < 128) {   // combine: thread = (b, jo)
      int b = tid >> 2, jo = tid & 3;
      int mt = b >> 4, rw = b & 15;
      const float* zb_ = zl + b * 48;
      float gv[4];
      #pragma unroll
      for (int kg = 0; kg < 4; kg++) {
        int n = kg * 4 + jo;
        float wh = red[(0 + mt) * 272 + rw * 17 + n] + red[(2 + mt) * 272 + rw * 17 + n]
                 + red[(4 + mt) * 272 + rw * 17 + n] + red[(6 + mt) * 272 + rw * 17 + n];
        float dxv = 0.f, dhv = 0.f, bdv = pbbl[jo];
        #pragma unroll
        for (int e = 0; e < 4; e++) {
          dxv += zb_[kg * 4 + e]      * pdl[0][e][jo];
          dhv += zb_[16 + kg * 4 + e] * pdl[1][e][jo];
          bdv += zb_[32 + kg * 4 + e] * pdl[2][e][jo];
        }
        float wxv = (kg == 0) ? wx0 : (kg == 1) ? wx1 : (kg == 2) ? wx2 : wx3;
        gv[kg] = wxv * dxv + wh * dhv + bdv;
      }
      float iv = 1.f / (1.f + __expf(-gv[0]));
      float fv = 1.f / (1.f + __expf(-gv[1]));
      float ov = 1.f / (1.f + __expf(-gv[2]));
      float gg = tanhf(gv[3]);
      float cn = fv * clds[tid] + iv * gg;
      clds[tid] = cn;
      float hn = ov * tanhf(cn);
      out[(size_t)(b * NT + t) * NH + jh0 + jo] = hn;
      hbuf[((t + 1) & 1) * (NB * NH) + b * NH + jh0 + jo] = f2bf(hn);
      if (t == NT - 1) {
        out[(size_t)NB * NT * NH + b * NH + jh0 + jo] = hn;
        out[(size_t)NB * NT * NH + NB * NH + b * NH + jh0 + jo] = cn;
      }
    }
    // grid barrier (agent-scope, monotonic counter; co-resident 256 blocks)
    tgt += NBLK;
    __syncthreads();
    if (tid == 0) {
      __threadfence();
      __hip_atomic_fetch_add(cnt, 1, __ATOMIC_RELEASE, __HIP_MEMORY_SCOPE_AGENT);
      while (__hip_atomic_load(cnt, __ATOMIC_ACQUIRE, __HIP_MEMORY_SCOPE_AGENT) < tgt)
        __builtin_amdgcn_s_sleep(1);
      __threadfence();
    }
    __syncthreads();
  }
}

// ---------------------------------------------------------------------------
extern "C" void kernel_launch(void* const* d_in, const int* in_sizes, int n_in,
                              void* d_out, int out_size, void* d_ws, size_t ws_size,
                              hipStream_t stream) {
  (void)in_sizes; (void)n_in; (void)out_size;
  const float* x    = (const float*)d_in[0];
  const float* Wm   = (const float*)d_in[1];
  const float* Wih  = (const float*)d_in[2];
  const float* Wix  = (const float*)d_in[3];
  const float* bi   = (const float*)d_in[4];
  const float* Wgh  = (const float*)d_in[5];
  const float* Wgx  = (const float*)d_in[6];
  const float* bg   = (const float*)d_in[7];
  const float* Wfh  = (const float*)d_in[8];
  const float* Wfx  = (const float*)d_in[9];
  const float* bfp  = (const float*)d_in[10];
  const float* Woh  = (const float*)d_in[11];
  const float* Wox  = (const float*)d_in[12];
  const float* bo   = (const float*)d_in[13];
  const float* lnig = (const float*)d_in[14];
  const float* lnib = (const float*)d_in[15];
  const float* lngg = (const float*)d_in[16];
  const float* lngb = (const float*)d_in[17];
  const float* lnfg = (const float*)d_in[18];
  const float* lnfb = (const float*)d_in[19];
  const float* lnog = (const float*)d_in[20];
  const float* lnob = (const float*)d_in[21];
  const float* lncg = (const float*)d_in[22];
  const float* lncb = (const float*)d_in[23];
  const float* pzxw = (const float*)d_in[24];
  const float* pzxb = (const float*)d_in[25];
  const float* pzhw = (const float*)d_in[26];
  const float* pzhb = (const float*)d_in[27];
  const float* pzbw = (const float*)d_in[28];
  const float* pzbb = (const float*)d_in[29];
  const float* pdx  = (const float*)d_in[30];
  const float* pdh  = (const float*)d_in[31];
  const float* pbw  = (const float*)d_in[32];
  const float* pbb  = (const float*)d_in[33];
  float* out = (float*)d_out;

  char* ws = (char*)d_ws;
  size_t off = 0;
  auto alloc = [&](size_t bytes) {
    char* p = ws + off; off += (bytes + 255) & ~(size_t)255; return p;
  };
  unsigned short* preall = (unsigned short*)alloc((size_t)16384 * NC4 * 2);
  unsigned short* wcat   = (unsigned short*)alloc((size_t)NC4 * 512 * 2);
  unsigned short* wmht   = (unsigned short*)alloc((size_t)4096 * 1024 * 2);
  unsigned short* whht   = (unsigned short*)alloc((size_t)4 * 128 * 128 * 2);
  float* pzt             = (float*)alloc((size_t)3 * 16 * 128 * 4);
  float* zbuf            = (float*)alloc((size_t)NT * NB * 48 * 4);
  unsigned short* hbuf   = (unsigned short*)alloc((size_t)2 * NB * NH * 2);
  int* cnt               = (int*)alloc(256);
  if (off > ws_size) return;  // ws too small: leave output untouched (diagnosable)

  k_prep<<<256, 256, 0, stream>>>(Wih, Wgh, Wfh, Woh, pzxw, pzhw, pzbw, whht, pzt, hbuf, cnt);
  k_twcat<<<2304, 256, 0, stream>>>(Wm, Wix, Wgx, Wfx, Wox, wcat);
  k_twmh<<<4096, 256, 0, stream>>>(Wm, wmht);
  k_gemm<<<4608, 256, 0, stream>>>(x, wcat, preall);
  k_hyper<<<32, 512, 0, stream>>>(preall, whht, pzt, bi, bg, bfp, bo,
      lnig, lnib, lngg, lngb, lnfg, lnfb, lnog, lnob, lncg, lncb,
      pzxb, pzhb, pzbb, zbuf);
  k_main<<<NBLK, 256, 0, stream>>>(preall, wmht, zbuf, pdx, pdh, pbw, pbb, hbuf, out, cnt);
}

// Round 2
// 6997.713 us; speedup vs baseline: 2.0629x; 2.0629x over previous
//
#include <hip/hip_runtime.h>
#include <cstdint>
#include <cstddef>

#define NB 32       // batch
#define NT 512      // time steps
#define ND 512      // input dim D
#define NH 1024     // hidden H
#define NC4 4608    // 4H + 4*HH (fused GEMM N)
#define NBLK 64     // main-kernel grid (16 h-cols per block)

typedef short sh8 __attribute__((ext_vector_type(8)));   // 8 bf16 (raw bits)
typedef float f4  __attribute__((ext_vector_type(4)));
typedef unsigned int u4 __attribute__((ext_vector_type(4)));

__device__ __forceinline__ unsigned short f2bf(float x) {
  union { float f; unsigned u; } v; v.f = x;
  unsigned r = v.u + 0x7FFFu + ((v.u >> 16) & 1u);   // RNE
  return (unsigned short)(r >> 16);
}
__device__ __forceinline__ float bf2f(unsigned short b) {
  union { unsigned u; float f; } v; v.u = ((unsigned)b) << 16; return v.f;
}
__device__ __forceinline__ float blo(unsigned w) { union { unsigned u; float f; } v; v.u = w << 16; return v.f; }
__device__ __forceinline__ float bhi(unsigned w) { union { unsigned u; float f; } v; v.u = w & 0xFFFF0000u; return v.f; }

// ---------------------------------------------------------------------------
// prep: hyper gate weights -> bf16 transposed [4][j=128][k=128];
//       pz weights -> fp32 [3][c=16][k=128]; zero h buf0; zero 64 flag lines
// ---------------------------------------------------------------------------
__global__ __launch_bounds__(256) void k_prep(
    const float* __restrict__ wih, const float* __restrict__ wgh,
    const float* __restrict__ wfh, const float* __restrict__ woh,
    const float* __restrict__ pzx, const float* __restrict__ pzh,
    const float* __restrict__ pzb,
    unsigned short* __restrict__ whht, float* __restrict__ pzt,
    unsigned short* __restrict__ hbuf, int* __restrict__ flags)
{
  int idx = blockIdx.x * 256 + threadIdx.x;
  if (idx < 65536) {  // 4*128*128
    int g = idx >> 14, r = idx & 16383, j = r >> 7, k = r & 127;
    const float* w = (g == 0) ? wih : (g == 1) ? wgh : (g == 2) ? wfh : woh;
    whht[idx] = f2bf(w[k * 128 + j]);
  }
  if (idx < 6144) {   // 3*16*128
    int r = idx & 2047, c = r >> 7, k = r & 127;
    int kind = idx >> 11;
    const float* p = (kind == 0) ? pzx : (kind == 1) ? pzh : pzb;
    pzt[idx] = p[k * 16 + c];
    (void)c; (void)k;
  }
  if (idx < 16384) ((unsigned int*)hbuf)[idx] = 0u;  // zero buf0 (32*1024 bf16)
  if (idx < 2048) flags[idx] = 0;                    // 64 flags x 32-int stride
}

// ---------------------------------------------------------------------------
// transpose Wcat -> bf16 [n=4608][k=512]: n<4096 from Wm[:512], else Wi/g/f/o_x
// ---------------------------------------------------------------------------
__global__ __launch_bounds__(256) void k_twcat(
    const float* __restrict__ wm, const float* __restrict__ wix,
    const float* __restrict__ wgx, const float* __restrict__ wfx,
    const float* __restrict__ wox, unsigned short* __restrict__ dst)
{
  __shared__ float tile[32][33];
  int bx = blockIdx.x % 144, by = blockIdx.x / 144;
  int n0 = bx * 32, k0 = by * 32;
  int tx = threadIdx.x & 31, ty = threadIdx.x >> 5;
  #pragma unroll
  for (int i = 0; i < 4; i++) {
    int k = k0 + ty + i * 8, n = n0 + tx;
    float v;
    if (n < 4096) v = wm[(size_t)k * 4096 + n];
    else {
      int nn = n - 4096, g = nn >> 7, j = nn & 127;
      const float* w = (g == 0) ? wix : (g == 1) ? wgx : (g == 2) ? wfx : wox;
      v = w[k * 128 + j];
    }
    tile[ty + i * 8][tx] = v;
  }
  __syncthreads();
  #pragma unroll
  for (int i = 0; i < 4; i++)
    dst[(size_t)(n0 + ty + i * 8) * 512 + k0 + tx] = f2bf(tile[tx][ty + i * 8]);
}

// transpose Wm[512:] -> bf16 [n=4096][k=1024]
__global__ __launch_bounds__(256) void k_twmh(
    const float* __restrict__ wm, unsigned short* __restrict__ dst)
{
  __shared__ float tile[32][33];
  int bx = blockIdx.x % 128, by = blockIdx.x / 128;
  int n0 = bx * 32, k0 = by * 32;
  int tx = threadIdx.x & 31, ty = threadIdx.x >> 5;
  #pragma unroll
  for (int i = 0; i < 4; i++)
    tile[ty + i * 8][tx] = wm[(size_t)(512 + k0 + ty + i * 8) * 4096 + n0 + tx];
  __syncthreads();
  #pragma unroll
  for (int i = 0; i < 4; i++)
    dst[(size_t)(n0 + ty + i * 8) * 1024 + k0 + tx] = f2bf(tile[tx][ty + i * 8]);
}

// ---------------------------------------------------------------------------
// Precompute GEMM: PreAll[t*32+b][n] = bf16( x[b*512+t][:] @ Wcat[:,n] )
// M=16384 K=512 N=4608, bf16 MFMA 16x16x32, 128x128 tile, 4 waves (2x2 of 64x64)
// ---------------------------------------------------------------------------
__global__ __launch_bounds__(256) void k_gemm(
    const float* __restrict__ x, const unsigned short* __restrict__ wt,
    unsigned short* __restrict__ preall)
{
  __shared__ unsigned short la[4096];  // [128 rows][32 k], XOR-swizzled 16B granules
  __shared__ unsigned short lb[4096];
  int bid = blockIdx.x;
  int mb = bid % 128, nb = bid / 128;
  int m0 = mb * 128, n0 = nb * 128;
  int tid = threadIdx.x;
  int lane = tid & 63, wid = tid >> 6;
  int wr = (wid >> 1) * 64, wc = (wid & 1) * 64;
  f4 acc[4][4] = {};
  for (int kt = 0; kt < 16; kt++) {
    int k0 = kt * 32;
    __syncthreads();
    {   // stage A (fp32 -> bf16): 2 threads/row, 16 floats each
      int r = tid >> 1, kh = (tid & 1) * 16;
      const float4* srcA = (const float4*)(x + (size_t)(m0 + r) * 512 + k0 + kh);
      unsigned pk[8];
      #pragma unroll
      for (int q = 0; q < 4; q++) {
        float4 f = srcA[q];
        pk[q * 2]     = (unsigned)f2bf(f.x) | ((unsigned)f2bf(f.y) << 16);
        pk[q * 2 + 1] = (unsigned)f2bf(f.z) | ((unsigned)f2bf(f.w) << 16);
      }
      int base = r * 64 + kh * 2;
      u4 v0 = {pk[0], pk[1], pk[2], pk[3]}, v1 = {pk[4], pk[5], pk[6], pk[7]};
      *(u4*)((char*)la + ((base)      ^ ((r & 7) << 4))) = v0;
      *(u4*)((char*)la + ((base + 16) ^ ((r & 7) << 4))) = v1;
    }
    {   // stage B (already bf16): 2 threads/row, 16 bf16 each
      int r = tid >> 1, kh = (tid & 1) * 16;
      const u4* srcB = (const u4*)(wt + (size_t)(n0 + r) * 512 + k0 + kh);
      u4 v0 = srcB[0], v1 = srcB[1];
      int base = r * 64 + kh * 2;
      *(u4*)((char*)lb + ((base)      ^ ((r & 7) << 4))) = v0;
      *(u4*)((char*)lb + ((base + 16) ^ ((r & 7) << 4))) = v1;
    }
    __syncthreads();
    int fo = (lane >> 4) * 16;
    sh8 af[4], bfr[4];
    #pragma unroll
    for (int mt = 0; mt < 4; mt++) {
      int r = wr + mt * 16 + (lane & 15);
      af[mt] = *(sh8*)((char*)la + ((r * 64 + fo) ^ ((r & 7) << 4)));
    }
    #pragma unroll
    for (int nt = 0; nt < 4; nt++) {
      int r = wc + nt * 16 + (lane & 15);
      bfr[nt] = *(sh8*)((char*)lb + ((r * 64 + fo) ^ ((r & 7) << 4)));
    }
    #pragma unroll
    for (int mt = 0; mt < 4; mt++)
      #pragma unroll
      for (int nt = 0; nt < 4; nt++)
        acc[mt][nt] = __builtin_amdgcn_mfma_f32_16x16x32_bf16(af[mt], bfr[nt], acc[mt][nt], 0, 0, 0);
  }
  // C write: row m -> (b=m>>9, t=m&511) -> PreAll row t*32+b, bf16
  #pragma unroll
  for (int mt = 0; mt < 4; mt++)
    #pragma unroll
    for (int nt = 0; nt < 4; nt++) {
      f4 a = acc[mt][nt];
      #pragma unroll
      for (int rr = 0; rr < 4; rr++) {
        int m = m0 + wr + mt * 16 + (lane >> 4) * 4 + rr;
        int n = n0 + wc + nt * 16 + (lane & 15);
        int b = m >> 9, t = m & 511;
        preall[(size_t)(t * 32 + b) * NC4 + n] = f2bf(a[rr]);
      }
    }
}

// ---------------------------------------------------------------------------
// Hyper chain: 1 block per batch row, 512 threads = (gate g, j).
// Gate weights live in VGPRs (bf16). Produces z[t][b][48] fp32.
// ---------------------------------------------------------------------------
__global__ __launch_bounds__(512) void k_hyper(
    const unsigned short* __restrict__ preall,  // xproj at cols 4096+
    const unsigned short* __restrict__ whht,    // [4][128][128] bf16
    const float* __restrict__ pzt,              // [3][16][128] fp32
    const float* __restrict__ bi, const float* __restrict__ bg,
    const float* __restrict__ bff, const float* __restrict__ bo,
    const float* __restrict__ lnig, const float* __restrict__ lnib,
    const float* __restrict__ lngg, const float* __restrict__ lngb,
    const float* __restrict__ lnfg, const float* __restrict__ lnfb,
    const float* __restrict__ lnog, const float* __restrict__ lnob,
    const float* __restrict__ lncg, const float* __restrict__ lncb,
    const float* __restrict__ pzxb, const float* __restrict__ pzhb,
    const float* __restrict__ pzbb,
    float* __restrict__ zout)
{
  const int b = blockIdx.x;
  const int tid = threadIdx.x;
  const int g = tid >> 7, j = tid & 127;
  __shared__ __align__(16) float hh[128];
  __shared__ __align__(16) float ch[128];
  __shared__ float act[4][128];
  __shared__ float red[20];
  __shared__ __align__(16) float pzl[48 * 132];  // padded rows (132) -> conflict-free

  u4 wreg[16];  // 128 bf16 weights for column (g,j)
  {
    const u4* wsrc = (const u4*)(whht + (size_t)(g * 128 + j) * 128);
    #pragma unroll
    for (int i = 0; i < 16; i++) wreg[i] = wsrc[i];
  }
  for (int i = tid; i < 6144; i += 512)
    pzl[(i >> 7) * 132 + (i & 127)] = pzt[i];

  float bias = ((g == 0) ? bi : (g == 1) ? bg : (g == 2) ? bff : bo)[j];
  float lgam = ((g == 0) ? lnig : (g == 1) ? lngg : (g == 2) ? lnfg : lnog)[j];
  float lbet = ((g == 0) ? lnib : (g == 1) ? lngb : (g == 2) ? lnfb : lnob)[j];
  float lcg = 0.f, lcb = 0.f;
  if (tid < 128) { lcg = lncg[tid]; lcb = lncb[tid]; hh[tid] = 0.f; ch[tid] = 0.f; }
  float zbias = 0.f;
  if (tid < 48) {
    int kind = tid >> 4, c = tid & 15;
    zbias = ((kind == 0) ? pzxb : (kind == 1) ? pzhb : pzbb)[c];
  }
  __syncthreads();

  const f4* h4 = (const f4*)hh;
  for (int t = 0; t < NT; t++) {
    float xp = bf2f(preall[(size_t)(t * 32 + b) * NC4 + 4096 + tid]);
    float s = bias;
    #pragma unroll
    for (int i = 0; i < 16; i++) {
      u4 w = wreg[i];
      f4 ha = h4[2 * i], hb = h4[2 * i + 1];
      s += blo(w.x) * ha[0] + bhi(w.x) * ha[1] + blo(w.y) * ha[2] + bhi(w.y) * ha[3]
         + blo(w.z) * hb[0] + bhi(w.z) * hb[1] + blo(w.w) * hb[2] + bhi(w.w) * hb[3];
    }
    s += xp;
    float s1 = s, s2 = s * s;
    #pragma unroll
    for (int m = 1; m < 64; m <<= 1) { s1 += __shfl_xor(s1, m); s2 += __shfl_xor(s2, m); }
    if ((tid & 63) == 0) { int w = tid >> 6; red[w * 2] = s1; red[w * 2 + 1] = s2; }
    __syncthreads();
    float sum = red[4 * g] + red[4 * g + 2], sq = red[4 * g + 1] + red[4 * g + 3];
    float mean = sum * 0.0078125f;
    float var = sq * 0.0078125f - mean * mean;
    float xn = (s - mean) * rsqrtf(var + 1e-5f) * lgam + lbet;
    float a = (g == 1) ? tanhf(xn) : 1.f / (1.f + __expf(-xn));
    act[g][j] = a;
    __syncthreads();
    if (tid < 128) {
      float cn = act[2][tid] * ch[tid] + act[0][tid] * act[1][tid];
      ch[tid] = cn;
      float c1 = cn, c2 = cn * cn;
      #pragma unroll
      for (int m = 1; m < 64; m <<= 1) { c1 += __shfl_xor(c1, m); c2 += __shfl_xor(c2, m); }
      if ((tid & 63) == 0) { int w = tid >> 6; red[16 + w * 2] = c1; red[16 + w * 2 + 1] = c2; }
    }
    __syncthreads();
    if (tid < 128) {
      float sum2 = red[16] + red[18], sq2 = red[17] + red[19];
      float mean2 = sum2 * 0.0078125f, var2 = sq2 * 0.0078125f - mean2 * mean2;
      float cn = ch[tid];
      hh[tid] = act[3][tid] * tanhf((cn - mean2) * rsqrtf(var2 + 1e-5f) * lcg + lcb);
    }
    __syncthreads();
    if (tid < 48) {   // z = hh_new @ pz*_w + pz*_b
      const f4* pr = (const f4*)(pzl + tid * 132);
      float zv = zbias;
      #pragma unroll 8
      for (int q = 0; q < 32; q++) {
        f4 p = pr[q], hv = h4[q];
        zv += p[0] * hv[0] + p[1] * hv[1] + p[2] * hv[2] + p[3] * hv[3];
      }
      zout[(size_t)(t * 32 + b) * 48 + tid] = zv;
    }
    __syncthreads();
  }
}

// ---------------------------------------------------------------------------
// Main recurrence: persistent 64 blocks x 256 thr. Block owns 16 h-cols
// (64 gate-cols). W slice (128KB bf16, swizzled) in LDS.
// Sync: all-to-all distributed flags (no RMW barrier). Producer: fence +
// release-store flag[bid]=t+1 (own 128B line). Consumer: wave0 RELAXED-polls
// all 64 flags, one fence, syncthreads. Double-buffered h makes this safe.
// ---------------------------------------------------------------------------
__global__ __launch_bounds__(256) void k_main(
    const unsigned short* __restrict__ preall,
    const unsigned short* __restrict__ wmht,
    const float* __restrict__ zbuf,
    const float* __restrict__ pdx, const float* __restrict__ pdh,
    const float* __restrict__ pbw, const float* __restrict__ pbb,
    unsigned short* __restrict__ hbuf,    // [2][32][1024] bf16 ping-pong
    float* __restrict__ out,
    int* __restrict__ flags)
{
  __shared__ unsigned short wlds[64 * 1024];   // [n=64][k=1024] bf16, XOR-swizzled (128KB)
  __shared__ float red[2][32][68];             // [K-half][b][n] partials (17.4KB)
  __shared__ __align__(16) float zl[32 * 48];  // z(t) staging (6KB)
  __shared__ float clds[512];                  // c state: [b][jo]
  __shared__ float pdl[3][4][16];
  __shared__ float pbbl[16];

  const int tid = threadIdx.x;
  const int lane = tid & 63, wid = tid >> 6;
  const int jh0 = blockIdx.x * 16;

  {   // stage weight slice once: n = g*16+jo -> wmht row g*NH + jh0 + jo
    int n = tid >> 2, kc = (tid & 3) * 256;
    int g = n >> 4, jo = n & 15;
    const unsigned short* src = wmht + (size_t)(g * NH + jh0 + jo) * NH + kc;
    #pragma unroll
    for (int i = 0; i < 32; i++) {
      sh8 v = *(const sh8*)(src + i * 8);
      int byte = n * 2048 + (kc + i * 8) * 2;
      *(sh8*)((char*)wlds + (byte ^ ((n & 7) << 4))) = v;
    }
  }
  clds[tid] = 0.f; clds[tid + 256] = 0.f;
  if (tid < 192) {
    int kind = tid >> 6, e = (tid >> 4) & 3, jo = tid & 15;
    const float* p = (kind == 0) ? pdx : (kind == 1) ? pdh : pbw;
    pdl[kind][e][jo] = p[e * NH + jh0 + jo];
  }
  if (tid < 16) pbbl[tid] = pbb[jh0 + tid];
  __syncthreads();

  const int bq = tid >> 3;    // combine row b: 0..31
  const int jo2 = tid & 7;    // combine col pair base: jo2, jo2+8

  for (int t = 0; t < NT; t++) {
    // ---- prefetch Wx + z into regs (independent of h(t)) -----------------
    float wx[2][4];
    {
      const unsigned short* ps = preall + (size_t)(t * NB + bq) * NC4 + jh0;
      #pragma unroll
      for (int g = 0; g < 4; g++) {
        wx[0][g] = bf2f(ps[g * NH + jo2]);
        wx[1][g] = bf2f(ps[g * NH + jo2 + 8]);
      }
    }
    f4 zr0 = {0, 0, 0, 0}, zr1 = {0, 0, 0, 0};
    if (tid < 192) {
      const f4* zs = (const f4*)(zbuf + (size_t)t * NB * 48) + tid * 2;
      zr0 = zs[0]; zr1 = zs[1];
    }
    // ---- wait for h(t) ---------------------------------------------------
    if (wid == 0) {
      for (;;) {
        int v = __hip_atomic_load(flags + lane * 32, __ATOMIC_RELAXED,
                                  __HIP_MEMORY_SCOPE_AGENT);
        if (__all(v >= t)) break;
        __builtin_amdgcn_s_sleep(1);
      }
      __threadfence();
    }
    __syncthreads();
    if (tid < 192) { f4* zd = (f4*)zl + tid * 2; zd[0] = zr0; zd[1] = zr1; }
    const unsigned short* hcur = hbuf + (t & 1) * (NB * NH);
    // ---- W_h: wave = (kh = K-half, nh = N-half); 4 indep 16-deep chains --
    {
      const int kh = wid >> 1, nh = wid & 1;
      const int koff = (lane >> 4) * 8;
      const int col = lane & 15;
      f4 acc[2][2] = {};
      #pragma unroll
      for (int ks = 0; ks < 16; ks++) {
        int kb = kh * 512 + ks * 32 + koff;
        int n0 = nh * 32 + col, n1 = nh * 32 + 16 + col;
        sh8 b0 = *(sh8*)((char*)wlds + ((n0 * 2048 + kb * 2) ^ ((n0 & 7) << 4)));
        sh8 b1 = *(sh8*)((char*)wlds + ((n1 * 2048 + kb * 2) ^ ((n1 & 7) << 4)));
        sh8 a0 = *(const sh8*)(hcur + col * NH + kb);
        sh8 a1 = *(const sh8*)(hcur + (16 + col) * NH + kb);
        acc[0][0] = __builtin_amdgcn_mfma_f32_16x16x32_bf16(a0, b0, acc[0][0], 0, 0, 0);
        acc[0][1] = __builtin_amdgcn_mfma_f32_16x16x32_bf16(a0, b1, acc[0][1], 0, 0, 0);
        acc[1][0] = __builtin_amdgcn_mfma_f32_16x16x32_bf16(a1, b0, acc[1][0], 0, 0, 0);
        acc[1][1] = __builtin_amdgcn_mfma_f32_16x16x32_bf16(a1, b1, acc[1][1], 0, 0, 0);
      }
      int r0 = (lane >> 4) * 4;
      #pragma unroll
      for (int mt = 0; mt < 2; mt++)
        #pragma unroll
        for (int nt = 0; nt < 2; nt++)
          #pragma unroll
          for (int rr = 0; rr < 4; rr++)
            red[kh][mt * 16 + r0 + rr][nh * 32 + nt * 16 + col] = acc[mt][nt][rr];
    }
    __syncthreads();
    // ---- combine: thread (bq, jo2) handles jo2 and jo2+8 -----------------
    const float* zb_ = zl + bq * 48;
    #pragma unroll
    for (int half = 0; half < 2; half++) {
      int jo = jo2 + half * 8;
      float gv[4];
      #pragma unroll
      for (int g = 0; g < 4; g++) {
        float wh = red[0][bq][g * 16 + jo] + red[1][bq][g * 16 + jo];
        float dxv = 0.f, dhv = 0.f, bdv = pbbl[jo];
        #pragma unroll
        for (int e = 0; e < 4; e++) {
          dxv += zb_[g * 4 + e]      * pdl[0][e][jo];
          dhv += zb_[16 + g * 4 + e] * pdl[1][e][jo];
          bdv += zb_[32 + g * 4 + e] * pdl[2][e][jo];
        }
        gv[g] = wx[half][g] * dxv + wh * dhv + bdv;
      }
      float iv = 1.f / (1.f + __expf(-gv[0]));
      float fv = 1.f / (1.f + __expf(-gv[1]));
      float ov = 1.f / (1.f + __expf(-gv[2]));
      float gg = tanhf(gv[3]);
      int ci = bq * 16 + jo;
      float cn = fv * clds[ci] + iv * gg;
      clds[ci] = cn;
      float hn = ov * tanhf(cn);
      out[(size_t)(bq * NT + t) * NH + jh0 + jo] = hn;
      hbuf[((t + 1) & 1) * (NB * NH) + bq * NH + jh0 + jo] = f2bf(hn);
      if (t == NT - 1) {
        out[(size_t)NB * NT * NH + bq * NH + jh0 + jo] = hn;
        out[(size_t)NB * NT * NH + NB * NH + bq * NH + jh0 + jo] = cn;
      }
    }
    // ---- publish h(t+1) --------------------------------------------------
    __syncthreads();   // drains all waves' h stores (vmcnt 0 at barrier)
    if (tid == 0) {
      __threadfence();
      __hip_atomic_store(flags + blockIdx.x * 32, t + 1, __ATOMIC_RELEASE,
                         __HIP_MEMORY_SCOPE_AGENT);
    }
  }
}

// ---------------------------------------------------------------------------
extern "C" void kernel_launch(void* const* d_in, const int* in_sizes, int n_in,
                              void* d_out, int out_size, void* d_ws, size_t ws_size,
                              hipStream_t stream) {
  (void)in_sizes; (void)n_in; (void)out_size;
  const float* x    = (const float*)d_in[0];
  const float* Wm   = (const float*)d_in[1];
  const float* Wih  = (const float*)d_in[2];
  const float* Wix  = (const float*)d_in[3];
  const float* bi   = (const float*)d_in[4];
  const float* Wgh  = (const float*)d_in[5];
  const float* Wgx  = (const float*)d_in[6];
  const float* bg   = (const float*)d_in[7];
  const float* Wfh  = (const float*)d_in[8];
  const float* Wfx  = (const float*)d_in[9];
  const float* bfp  = (const float*)d_in[10];
  const float* Woh  = (const float*)d_in[11];
  const float* Wox  = (const float*)d_in[12];
  const float* bo   = (const float*)d_in[13];
  const float* lnig = (const float*)d_in[14];
  const float* lnib = (const float*)d_in[15];
  const float* lngg = (const float*)d_in[16];
  const float* lngb = (const float*)d_in[17];
  const float* lnfg = (const float*)d_in[18];
  const float* lnfb = (const float*)d_in[19];
  const float* lnog = (const float*)d_in[20];
  const float* lnob = (const float*)d_in[21];
  const float* lncg = (const float*)d_in[22];
  const float* lncb = (const float*)d_in[23];
  const float* pzxw = (const float*)d_in[24];
  const float* pzxb = (const float*)d_in[25];
  const float* pzhw = (const float*)d_in[26];
  const float* pzhb = (const float*)d_in[27];
  const float* pzbw = (const float*)d_in[28];
  const float* pzbb = (const float*)d_in[29];
  const float* pdx  = (const float*)d_in[30];
  const float* pdh  = (const float*)d_in[31];
  const float* pbw  = (const float*)d_in[32];
  const float* pbb  = (const float*)d_in[33];
  float* out = (float*)d_out;

  char* ws = (char*)d_ws;
  size_t off = 0;
  auto alloc = [&](size_t bytes) {
    char* p = ws + off; off += (bytes + 255) & ~(size_t)255; return p;
  };
  unsigned short* preall = (unsigned short*)alloc((size_t)16384 * NC4 * 2);
  unsigned short* wcat   = (unsigned short*)alloc((size_t)NC4 * 512 * 2);
  unsigned short* wmht   = (unsigned short*)alloc((size_t)4096 * 1024 * 2);
  unsigned short* whht   = (unsigned short*)alloc((size_t)4 * 128 * 128 * 2);
  float* pzt             = (float*)alloc((size_t)3 * 16 * 128 * 4);
  float* zbuf            = (float*)alloc((size_t)NT * NB * 48 * 4);
  unsigned short* hbuf   = (unsigned short*)alloc((size_t)2 * NB * NH * 2);
  int* flags             = (int*)alloc((size_t)64 * 32 * 4);
  if (off > ws_size) return;  // ws too small: leave output untouched (diagnosable)

  k_prep<<<256, 256, 0, stream>>>(Wih, Wgh, Wfh, Woh, pzxw, pzhw, pzbw, whht, pzt, hbuf, flags);
  k_twcat<<<2304, 256, 0, stream>>>(Wm, Wix, Wgx, Wfx, Wox, wcat);
  k_twmh<<<4096, 256, 0, stream>>>(Wm, wmht);
  k_gemm<<<4608, 256, 0, stream>>>(x, wcat, preall);
  k_hyper<<<32, 512, 0, stream>>>(preall, whht, pzt, bi, bg, bfp, bo,
      lnig, lnib, lngg, lngb, lnfg, lnfb, lnog, lnob, lncg, lncb,
      pzxb, pzhb, pzbb, zbuf);
  k_main<<<NBLK, 256, 0, stream>>>(preall, wmht, zbuf, pdx, pdh, pbw, pbb, hbuf, out, flags);
}